// Round 6
// baseline (1002.036 us; speedup 1.0000x reference)
//
#include <hip/hip_runtime.h>
#include <hip/hip_bf16.h>

#define N_NODES 100000
#define N_EDGES 1600000
#define IN_F 128
#define OUT_F 64

#define RPB 64                      // rows per bucket
#define NB  1563                    // ceil(100000/64)

typedef __attribute__((ext_vector_type(8))) short short8;   // 8 bf16 = 4 VGPR
typedef __attribute__((ext_vector_type(4))) float f32x4;

#define LDS_PITCH 136   // 128 + 8 pad; row stride 272 B

__device__ __forceinline__ unsigned short f2bf(float x) {
    unsigned u = __float_as_uint(x);
    return (unsigned short)((u + 0x7FFFu + ((u >> 16) & 1u)) >> 16);  // RNE
}

// ---------------------------------------------------------------------------
// K0: wa1 = W @ a1, wa2 = W @ a2  (makes f1/f2 exact-fp32 in k_gemm)
// ---------------------------------------------------------------------------
__global__ __launch_bounds__(128) void k_wa(
    const float* __restrict__ W,
    const float* __restrict__ a1,
    const float* __restrict__ a2,
    float* __restrict__ wa1,
    float* __restrict__ wa2)
{
    const int k = threadIdx.x;   // 0..127
    float s1 = 0.f, s2 = 0.f;
    #pragma unroll 8
    for (int f = 0; f < OUT_F; f++) {
        const float w = W[k * OUT_F + f];
        s1 += w * a1[f];
        s2 += w * a2[f];
    }
    wa1[k] = s1;
    wa2[k] = s2;
}

// ---------------------------------------------------------------------------
// K1: Wh = h @ W via bf16 MFMA (fp32 accum); f1/f2 fused in fp32. (proven)
// ---------------------------------------------------------------------------
__global__ __launch_bounds__(256) void k_gemm(
    const float* __restrict__ h,
    const float* __restrict__ W,
    const float* __restrict__ wa1,
    const float* __restrict__ wa2,
    float* __restrict__ Wh,
    float* __restrict__ f1,
    float* __restrict__ f2)
{
    __shared__ unsigned short Wt[OUT_F * LDS_PITCH];
    __shared__ unsigned short Al[16 * LDS_PITCH];

    const int tid  = threadIdx.x;
    const int lane = tid & 63;
    const int wav  = tid >> 6;
    const int quad = lane >> 4;
    const int nl   = lane & 15;

    for (int i = tid; i < IN_F * OUT_F; i += 256) {
        const int k = i >> 6, f = i & 63;
        Wt[f * LDS_PITCH + k] = f2bf(W[i]);
    }
    __syncthreads();

    short8 bfrag[4];
    #pragma unroll
    for (int ch = 0; ch < 4; ch++) {
        const int row = wav * 16 + nl;
        const int kb  = ch * 32 + quad * 8;
        bfrag[ch] = *(const short8*)&Wt[row * LDS_PITCH + kb];
    }

    const int srow = tid >> 4;
    const int sc   = tid & 15;
    float w1r[8], w2r[8];
    #pragma unroll
    for (int j = 0; j < 8; j++) { w1r[j] = wa1[sc * 8 + j]; w2r[j] = wa2[sc * 8 + j]; }

    const int ntiles = N_NODES / 16;   // 6250
    for (int tile = blockIdx.x; tile < ntiles; tile += gridDim.x) {
        const int base = tile * 16;

        __syncthreads();

        const float4 v0 = *(const float4*)&h[(base + srow) * IN_F + sc * 8];
        const float4 v1 = *(const float4*)&h[(base + srow) * IN_F + sc * 8 + 4];
        float p1 = v0.x * w1r[0] + v0.y * w1r[1] + v0.z * w1r[2] + v0.w * w1r[3]
                 + v1.x * w1r[4] + v1.y * w1r[5] + v1.z * w1r[6] + v1.w * w1r[7];
        float p2 = v0.x * w2r[0] + v0.y * w2r[1] + v0.z * w2r[2] + v0.w * w2r[3]
                 + v1.x * w2r[4] + v1.y * w2r[5] + v1.z * w2r[6] + v1.w * w2r[7];
        #pragma unroll
        for (int m = 8; m >= 1; m >>= 1) {
            p1 += __shfl_xor(p1, m, 64);
            p2 += __shfl_xor(p2, m, 64);
        }
        if (sc == 0) { f1[base + srow] = p1; f2[base + srow] = p2; }

        uint4 packed;
        packed.x = (unsigned)f2bf(v0.x) | ((unsigned)f2bf(v0.y) << 16);
        packed.y = (unsigned)f2bf(v0.z) | ((unsigned)f2bf(v0.w) << 16);
        packed.z = (unsigned)f2bf(v1.x) | ((unsigned)f2bf(v1.y) << 16);
        packed.w = (unsigned)f2bf(v1.z) | ((unsigned)f2bf(v1.w) << 16);
        *(uint4*)&Al[srow * LDS_PITCH + sc * 8] = packed;

        __syncthreads();

        f32x4 acc = {0.f, 0.f, 0.f, 0.f};
        #pragma unroll
        for (int ch = 0; ch < 4; ch++) {
            const short8 afrag = *(const short8*)&Al[nl * LDS_PITCH + ch * 32 + quad * 8];
            acc = __builtin_amdgcn_mfma_f32_16x16x32_bf16(afrag, bfrag[ch], acc, 0, 0, 0);
        }

        const int col = wav * 16 + nl;
        #pragma unroll
        for (int r = 0; r < 4; r++)
            Wh[(base + quad * 4 + r) * OUT_F + col] = acc[r];
    }
}

// ---------------------------------------------------------------------------
// K2: bucket histogram via LDS (hist pre-zeroed). bucket = row >> 6.
// ---------------------------------------------------------------------------
__global__ __launch_bounds__(256) void k_hist(const int* __restrict__ ei,
                                              int* __restrict__ hist)
{
    __shared__ int hl[NB];
    for (int i = threadIdx.x; i < NB; i += 256) hl[i] = 0;
    __syncthreads();
    const int stride = gridDim.x * 256;
    for (int e = blockIdx.x * 256 + threadIdx.x; e < N_EDGES; e += stride)
        atomicAdd(&hl[ei[e] >> 6], 1);
    __syncthreads();
    for (int i = threadIdx.x; i < NB; i += 256)
        if (hl[i]) atomicAdd(&hist[i], hl[i]);
}

// ---------------------------------------------------------------------------
// K3: exclusive scan of NB bucket counts (single block). base: NB+1, cur: NB.
// ---------------------------------------------------------------------------
__global__ __launch_bounds__(256) void k_scan(const int* __restrict__ hist,
                                              int* __restrict__ base,
                                              int* __restrict__ cur)
{
    __shared__ int ts[256];
    const int t = threadIdx.x;
    int v[7]; int s = 0;
    #pragma unroll
    for (int k = 0; k < 7; k++) {
        const int i = t * 7 + k;
        v[k] = (i < NB) ? hist[i] : 0;
        s += v[k];
    }
    ts[t] = s; __syncthreads();
    for (int off = 1; off < 256; off <<= 1) {       // inclusive Hillis-Steele
        int x = (t >= off) ? ts[t - off] : 0;
        __syncthreads();
        ts[t] += x;
        __syncthreads();
    }
    int excl = ts[t] - s;
    #pragma unroll
    for (int k = 0; k < 7; k++) {
        const int i = t * 7 + k;
        if (i < NB) { base[i] = excl; cur[i] = excl; }
        excl += v[k];
    }
    if (t == 255) base[NB] = N_EDGES;
}

// ---------------------------------------------------------------------------
// K4: bucketed scatter. pos = atomicAdd(&cur[bucket],1) -> sequential slots
// per bucket (dense line packing). pair = {(rlocal<<17)|col, eexp}.
// 4 edges/thread, phase-unrolled for ILP. 1250 blocks x 320 = 400000 exact.
// ---------------------------------------------------------------------------
__global__ __launch_bounds__(320) void k_scatter(
    const int* __restrict__ ei,
    const float* __restrict__ f1,
    const float* __restrict__ f2,
    int* __restrict__ cur,
    uint2* __restrict__ pairs)
{
    const int t = blockIdx.x * 320 + threadIdx.x;   // [0, 400000)
    int r[4], c[4];
    #pragma unroll
    for (int k = 0; k < 4; k++) {
        const int e = k * 400000 + t;
        r[k] = ei[e];
        c[k] = ei[N_EDGES + e];
    }
    float ee[4]; int bk[4];
    #pragma unroll
    for (int k = 0; k < 4; k++) {
        float x = f1[r[k]] + f2[c[k]];
        x = (x >= 0.f) ? x : 0.2f * x;
        ee[k] = __expf(x);
        bk[k] = r[k] >> 6;
    }
    int pos[4];
    #pragma unroll
    for (int k = 0; k < 4; k++) pos[k] = atomicAdd(&cur[bk[k]], 1);
    #pragma unroll
    for (int k = 0; k < 4; k++)
        pairs[pos[k]] = make_uint2(((unsigned)(r[k] & 63) << 17) | (unsigned)c[k],
                                   __float_as_uint(ee[k]));
}

// ---------------------------------------------------------------------------
// K5: bucket-per-block aggregation. Pairs staged via LDS (coalesced);
// per-edge ds_add_f32 into acc[64][64] (bank = lane%32 -> 2-way, free).
// Epilogue: out = elu(acc / (ssum + eps)). Zero-degree rows -> elu(0) = 0.
// ---------------------------------------------------------------------------
__global__ __launch_bounds__(256) void k_agg(
    const int* __restrict__ base,
    const uint2* __restrict__ pairs,
    const float* __restrict__ Wh,
    float* __restrict__ out)
{
    __shared__ float acc[RPB * OUT_F];   // 16 KB
    __shared__ float ssum[RPB];
    __shared__ uint2 stage[256];         // 2 KB

    const int b   = blockIdx.x;
    const int tid = threadIdx.x;
    const int lane = tid & 63;
    const int wav  = tid >> 6;

    for (int i = tid; i < RPB * OUT_F; i += 256) acc[i] = 0.f;
    if (tid < RPB) ssum[tid] = 0.f;

    const int start = base[b];
    const int cnt   = base[b + 1] - start;
    __syncthreads();

    for (int ch = 0; ch < cnt; ch += 256) {
        const int n = min(256, cnt - ch);
        if (tid < n) stage[tid] = pairs[start + ch + tid];
        __syncthreads();
        const int w0 = wav * 64;
        const int m  = min(64, max(0, n - w0));
        for (int i = 0; i < m; i++) {
            const uint2 p = stage[w0 + i];          // wave-uniform -> broadcast
            const int   c  = (int)(p.x & 0x1FFFFu);
            const int   rl = (int)(p.x >> 17);
            const float ee = __uint_as_float(p.y);
            const float wh = Wh[(c << 6) + lane];   // 256B coalesced gather
            atomicAdd(&acc[(rl << 6) + lane], ee * wh);
            if (lane == 0) atomicAdd(&ssum[rl], ee);
        }
        __syncthreads();
    }

    const int gbase = b << 6;
    for (int i = tid; i < RPB * OUT_F; i += 256) {
        const int rl = i >> 6, col = i & 63;
        const int g = gbase + rl;
        if (g < N_NODES) {
            const float r = acc[i] / (ssum[rl] + 1e-10f);
            out[(g << 6) + col] = (r > 0.f) ? r : expm1f(r);
        }
    }
}

extern "C" void kernel_launch(void* const* d_in, const int* in_sizes, int n_in,
                              void* d_out, int out_size, void* d_ws, size_t ws_size,
                              hipStream_t stream) {
    const float* h  = (const float*)d_in[0];
    const float* W  = (const float*)d_in[1];
    const float* a1 = (const float*)d_in[2];
    const float* a2 = (const float*)d_in[3];
    const int* ei   = (const int*)d_in[4];
    float* out      = (float*)d_out;

    float* ws   = (float*)d_ws;
    float* Wh   = ws;                          // 6,400,000
    float* f1   = Wh + N_NODES * OUT_F;        // 100,000
    float* f2   = f1 + N_NODES;                // 100,000
    float* wa1  = f2 + N_NODES;                // 128
    float* wa2  = wa1 + 128;                   // 128
    int*   hist = (int*)(wa2 + 128);           // NB
    int*   base = hist + NB;                   // NB+1
    int*   cur  = base + NB + 1;               // NB
    uint2* pairs = (uint2*)(cur + NB);         // E x 8B (8B-aligned: word ofs even)

    hipMemsetAsync(hist, 0, NB * sizeof(int), stream);

    k_wa     <<<1, 128, 0, stream>>>(W, a1, a2, wa1, wa2);
    k_gemm   <<<1250, 256, 0, stream>>>(h, W, wa1, wa2, Wh, f1, f2);
    k_hist   <<<120, 256, 0, stream>>>(ei, hist);
    k_scan   <<<1, 256, 0, stream>>>(hist, base, cur);
    k_scatter<<<1250, 320, 0, stream>>>(ei, f1, f2, cur, pairs);
    k_agg    <<<NB, 256, 0, stream>>>(base, pairs, Wh, out);
}

// Round 7
// 902.065 us; speedup vs baseline: 1.1108x; 1.1108x over previous
//
#include <hip/hip_runtime.h>
#include <hip/hip_bf16.h>

#define N_NODES 100000
#define N_EDGES 1600000
#define IN_F 128
#define OUT_F 64

#define RPB 64                        // rows per bucket
#define NB  1563                      // ceil(100000/64)
#define C_CHUNKS 250                  // edge chunks (scatter/hist blocks)
#define CHUNK 6400                    // edges per chunk; 250*6400 = 1,600,000
#define M_CNT (NB * C_CHUNKS)         // 390,750 flattened (bucket-major) counters
#define SCANA_BLOCKS ((M_CNT + 1023) / 1024)   // 382

typedef __attribute__((ext_vector_type(8))) short short8;
typedef __attribute__((ext_vector_type(4))) float f32x4;

#define LDS_PITCH 136

__device__ __forceinline__ unsigned short f2bf(float x) {
    unsigned u = __float_as_uint(x);
    return (unsigned short)((u + 0x7FFFu + ((u >> 16) & 1u)) >> 16);  // RNE
}

// ---------------------------------------------------------------------------
// K0: wa1 = W @ a1, wa2 = W @ a2  (keeps f1/f2 exact fp32 in k_gemm)
// ---------------------------------------------------------------------------
__global__ __launch_bounds__(128) void k_wa(
    const float* __restrict__ W, const float* __restrict__ a1,
    const float* __restrict__ a2, float* __restrict__ wa1, float* __restrict__ wa2)
{
    const int k = threadIdx.x;
    float s1 = 0.f, s2 = 0.f;
    #pragma unroll 8
    for (int f = 0; f < OUT_F; f++) {
        const float w = W[k * OUT_F + f];
        s1 += w * a1[f];
        s2 += w * a2[f];
    }
    wa1[k] = s1;
    wa2[k] = s2;
}

// ---------------------------------------------------------------------------
// K1: Wh = h @ W via bf16 MFMA; f1/f2 fused in fp32.  (unchanged, proven)
// ---------------------------------------------------------------------------
__global__ __launch_bounds__(256) void k_gemm(
    const float* __restrict__ h, const float* __restrict__ W,
    const float* __restrict__ wa1, const float* __restrict__ wa2,
    float* __restrict__ Wh, float* __restrict__ f1, float* __restrict__ f2)
{
    __shared__ unsigned short Wt[OUT_F * LDS_PITCH];
    __shared__ unsigned short Al[16 * LDS_PITCH];

    const int tid  = threadIdx.x;
    const int lane = tid & 63;
    const int wav  = tid >> 6;
    const int quad = lane >> 4;
    const int nl   = lane & 15;

    for (int i = tid; i < IN_F * OUT_F; i += 256) {
        const int k = i >> 6, f = i & 63;
        Wt[f * LDS_PITCH + k] = f2bf(W[i]);
    }
    __syncthreads();

    short8 bfrag[4];
    #pragma unroll
    for (int ch = 0; ch < 4; ch++)
        bfrag[ch] = *(const short8*)&Wt[(wav * 16 + nl) * LDS_PITCH + ch * 32 + quad * 8];

    const int srow = tid >> 4;
    const int sc   = tid & 15;
    float w1r[8], w2r[8];
    #pragma unroll
    for (int j = 0; j < 8; j++) { w1r[j] = wa1[sc * 8 + j]; w2r[j] = wa2[sc * 8 + j]; }

    const int ntiles = N_NODES / 16;
    for (int tile = blockIdx.x; tile < ntiles; tile += gridDim.x) {
        const int base = tile * 16;
        __syncthreads();

        const float4 v0 = *(const float4*)&h[(base + srow) * IN_F + sc * 8];
        const float4 v1 = *(const float4*)&h[(base + srow) * IN_F + sc * 8 + 4];
        float p1 = v0.x * w1r[0] + v0.y * w1r[1] + v0.z * w1r[2] + v0.w * w1r[3]
                 + v1.x * w1r[4] + v1.y * w1r[5] + v1.z * w1r[6] + v1.w * w1r[7];
        float p2 = v0.x * w2r[0] + v0.y * w2r[1] + v0.z * w2r[2] + v0.w * w2r[3]
                 + v1.x * w2r[4] + v1.y * w2r[5] + v1.z * w2r[6] + v1.w * w2r[7];
        #pragma unroll
        for (int m = 8; m >= 1; m >>= 1) {
            p1 += __shfl_xor(p1, m, 64);
            p2 += __shfl_xor(p2, m, 64);
        }
        if (sc == 0) { f1[base + srow] = p1; f2[base + srow] = p2; }

        uint4 packed;
        packed.x = (unsigned)f2bf(v0.x) | ((unsigned)f2bf(v0.y) << 16);
        packed.y = (unsigned)f2bf(v0.z) | ((unsigned)f2bf(v0.w) << 16);
        packed.z = (unsigned)f2bf(v1.x) | ((unsigned)f2bf(v1.y) << 16);
        packed.w = (unsigned)f2bf(v1.z) | ((unsigned)f2bf(v1.w) << 16);
        *(uint4*)&Al[srow * LDS_PITCH + sc * 8] = packed;

        __syncthreads();

        f32x4 acc = {0.f, 0.f, 0.f, 0.f};
        #pragma unroll
        for (int ch = 0; ch < 4; ch++) {
            const short8 afrag = *(const short8*)&Al[nl * LDS_PITCH + ch * 32 + quad * 8];
            acc = __builtin_amdgcn_mfma_f32_16x16x32_bf16(afrag, bfrag[ch], acc, 0, 0, 0);
        }

        const int col = wav * 16 + nl;
        #pragma unroll
        for (int r = 0; r < 4; r++)
            Wh[(base + quad * 4 + r) * OUT_F + col] = acc[r];
    }
}

// ---------------------------------------------------------------------------
// K2: per-chunk bucket histogram -> cnt[b * C_CHUNKS + c]  (bucket-major).
// Block c handles edges [c*CHUNK, (c+1)*CHUNK). LDS atomics only.
// Writes ALL buckets (incl. zeros) -> no global memset needed.
// ---------------------------------------------------------------------------
__global__ __launch_bounds__(1024) void k_hist(const int* __restrict__ ei,
                                               int* __restrict__ cnt)
{
    __shared__ int hl[NB];
    const int c = blockIdx.x;
    for (int i = threadIdx.x; i < NB; i += 1024) hl[i] = 0;
    __syncthreads();
    const int e0 = c * CHUNK;
    for (int i = threadIdx.x; i < CHUNK; i += 1024)
        atomicAdd(&hl[ei[e0 + i] >> 6], 1);
    __syncthreads();
    for (int b = threadIdx.x; b < NB; b += 1024)
        cnt[b * C_CHUNKS + c] = hl[b];
}

// ---------------------------------------------------------------------------
// K3a/b/c: exclusive scan of cnt[M_CNT], in place. 1024 elems per scanA block.
// ---------------------------------------------------------------------------
__global__ __launch_bounds__(256) void k_scanA(const int* __restrict__ cnt,
                                               int* __restrict__ bsum)
{
    __shared__ int sd[256];
    const int t = threadIdx.x;
    const int i0 = blockIdx.x * 1024 + t * 4;
    int s = 0;
    #pragma unroll
    for (int k = 0; k < 4; k++) {
        const int i = i0 + k;
        s += (i < M_CNT) ? cnt[i] : 0;
    }
    sd[t] = s; __syncthreads();
    for (int off = 128; off >= 1; off >>= 1) {
        if (t < off) sd[t] += sd[t + off];
        __syncthreads();
    }
    if (t == 0) bsum[blockIdx.x] = sd[0];
}

__global__ __launch_bounds__(512) void k_scanB(const int* __restrict__ bsum,
                                               int* __restrict__ bbase)
{
    __shared__ int s[512];
    const int t = threadIdx.x;
    const int mine = (t < SCANA_BLOCKS) ? bsum[t] : 0;
    s[t] = mine; __syncthreads();
    for (int off = 1; off < 512; off <<= 1) {
        const int v = (t >= off) ? s[t - off] : 0;
        __syncthreads();
        s[t] += v;
        __syncthreads();
    }
    if (t < SCANA_BLOCKS) bbase[t] = s[t] - mine;
}

__global__ __launch_bounds__(256) void k_scanC(int* __restrict__ cnt,
                                               const int* __restrict__ bbase)
{
    __shared__ int ts[256];
    const int t = threadIdx.x;
    const int i0 = blockIdx.x * 1024 + t * 4;
    int v[4]; int s = 0;
    #pragma unroll
    for (int k = 0; k < 4; k++) {
        const int i = i0 + k;
        v[k] = (i < M_CNT) ? cnt[i] : 0;
        s += v[k];
    }
    ts[t] = s; __syncthreads();
    for (int off = 1; off < 256; off <<= 1) {
        const int x = (t >= off) ? ts[t - off] : 0;
        __syncthreads();
        ts[t] += x;
        __syncthreads();
    }
    int excl = ts[t] - s + bbase[blockIdx.x];
    #pragma unroll
    for (int k = 0; k < 4; k++) {
        const int i = i0 + k;
        if (i < M_CNT) cnt[i] = excl;   // in-place: same thread read v[k] already
        excl += v[k];
    }
}

// ---------------------------------------------------------------------------
// K4: binned scatter, NO global atomics. Block c loads its private cursors
// cur[b] = cnt[b*C + c] into LDS; LDS-atomic cursor bump (block-local, ~4-way);
// pair = {(rlocal<<17)|col, eexp} into a dense private subrange.
// ---------------------------------------------------------------------------
__global__ __launch_bounds__(1024) void k_scatter(
    const int* __restrict__ ei,
    const float* __restrict__ f1,
    const float* __restrict__ f2,
    const int* __restrict__ cnt,
    uint2* __restrict__ pairs)
{
    __shared__ int cur[NB];
    const int c = blockIdx.x;
    for (int b = threadIdx.x; b < NB; b += 1024)
        cur[b] = cnt[b * C_CHUNKS + c];
    __syncthreads();

    const int e0 = c * CHUNK;
    for (int i = threadIdx.x; i < CHUNK; i += 1024) {
        const int r  = ei[e0 + i];
        const int cl = ei[N_EDGES + e0 + i];
        float x = f1[r] + f2[cl];
        x = (x >= 0.f) ? x : 0.2f * x;
        const float ee = __expf(x);
        const int pos = atomicAdd(&cur[r >> 6], 1);
        pairs[pos] = make_uint2(((unsigned)(r & 63) << 17) | (unsigned)cl,
                                __float_as_uint(ee));
    }
}

// ---------------------------------------------------------------------------
// K5: bucket-per-block aggregation with 8-deep gather ILP.
// Per wave: 64 pairs loaded coalesced (1/lane), shuffle-broadcast in groups
// of 8 -> 8 independent Wh gathers in flight -> ds_add_f32 (fire-and-forget).
// ---------------------------------------------------------------------------
__global__ __launch_bounds__(256) void k_agg(
    const int* __restrict__ cnt,      // scanned; bucket start = cnt[b*C]
    const uint2* __restrict__ pairs,
    const float* __restrict__ Wh,
    float* __restrict__ out)
{
    __shared__ float acc[RPB * OUT_F];   // 16 KB
    __shared__ float ssum[RPB];

    const int b    = blockIdx.x;
    const int tid  = threadIdx.x;
    const int lane = tid & 63;
    const int wav  = tid >> 6;

    for (int i = tid; i < RPB * OUT_F; i += 256) acc[i] = 0.f;
    if (tid < RPB) ssum[tid] = 0.f;

    const int start = cnt[b * C_CHUNKS];
    const int end   = (b == NB - 1) ? N_EDGES : cnt[(b + 1) * C_CHUNKS];
    const int total = end - start;
    // wave-private subrange
    const int ws_ = start + (int)(((long long)total * wav) >> 2);
    const int we_ = start + (int)(((long long)total * (wav + 1)) >> 2);
    __syncthreads();

    for (int g = ws_; g < we_; g += 64) {
        const int n = we_ - g;
        uint2 myp = make_uint2(0u, 0u);          // ee=0 -> harmless filler
        if (lane < n) myp = pairs[g + lane];

        #pragma unroll
        for (int j = 0; j < 64; j += 8) {
            float wh8[8], ee8[8]; int rl8[8];
            #pragma unroll
            for (int k = 0; k < 8; k++) {
                const unsigned px = __shfl(myp.x, j + k, 64);
                const unsigned py = __shfl(myp.y, j + k, 64);
                const int col = (int)(px & 0x1FFFFu);
                rl8[k] = (int)(px >> 17);
                ee8[k] = __uint_as_float(py);
                wh8[k] = Wh[(col << 6) + lane];   // 8 independent 256B gathers
            }
            #pragma unroll
            for (int k = 0; k < 8; k++) {
                atomicAdd(&acc[(rl8[k] << 6) + lane], ee8[k] * wh8[k]);
                if (lane == 0) atomicAdd(&ssum[rl8[k]], ee8[k]);
            }
        }
    }
    __syncthreads();

    const int gbase = b << 6;
    for (int i = tid; i < RPB * OUT_F; i += 256) {
        const int rl = i >> 6, col = i & 63;
        const int g = gbase + rl;
        if (g < N_NODES) {
            const float r = acc[i] / (ssum[rl] + 1e-10f);
            out[(g << 6) + col] = (r > 0.f) ? r : expm1f(r);
        }
    }
}

extern "C" void kernel_launch(void* const* d_in, const int* in_sizes, int n_in,
                              void* d_out, int out_size, void* d_ws, size_t ws_size,
                              hipStream_t stream) {
    const float* h  = (const float*)d_in[0];
    const float* W  = (const float*)d_in[1];
    const float* a1 = (const float*)d_in[2];
    const float* a2 = (const float*)d_in[3];
    const int* ei   = (const int*)d_in[4];
    float* out      = (float*)d_out;

    float* ws   = (float*)d_ws;
    float* Wh   = ws;                              // 6,400,000 f
    float* f1   = Wh + N_NODES * OUT_F;            // 100,000
    float* f2   = f1 + N_NODES;                    // 100,000
    float* wa1  = f2 + N_NODES;                    // 128
    float* wa2  = wa1 + 128;                       // 128
    int*   cnt  = (int*)(wa2 + 128);               // M_CNT = 390,750
    int*   bsum = cnt + M_CNT;                     // 384 (pad)
    int*   bbase= bsum + 384;                      // 384
    int*   pad  = bbase + 384;                     // align to 8B
    size_t w = (size_t)(pad - (int*)ws);
    if (w & 1) pad++;
    uint2* pairs = (uint2*)pad;                    // 1.6M x 8B

    k_wa     <<<1, 128, 0, stream>>>(W, a1, a2, wa1, wa2);
    k_gemm   <<<1250, 256, 0, stream>>>(h, W, wa1, wa2, Wh, f1, f2);
    k_hist   <<<C_CHUNKS, 1024, 0, stream>>>(ei, cnt);
    k_scanA  <<<SCANA_BLOCKS, 256, 0, stream>>>(cnt, bsum);
    k_scanB  <<<1, 512, 0, stream>>>(bsum, bbase);
    k_scanC  <<<SCANA_BLOCKS, 256, 0, stream>>>(cnt, bbase);
    k_scatter<<<C_CHUNKS, 1024, 0, stream>>>(ei, f1, f2, cnt, pairs);
    k_agg    <<<NB, 256, 0, stream>>>(cnt, pairs, Wh, out);
}

// Round 8
// 253.761 us; speedup vs baseline: 3.9487x; 3.5548x over previous
//
#include <hip/hip_runtime.h>
#include <hip/hip_bf16.h>

#define N_NODES 100000
#define N_EDGES 1600000
#define IN_F 128
#define OUT_F 64

#define RPB 64                        // rows per bucket
#define NB  1563                      // ceil(100000/64)
#define C_CHUNKS 250                  // edge chunks (scatter/hist blocks)
#define CHUNK 6400                    // edges per chunk; 250*6400 = 1,600,000
#define M_CNT (NB * C_CHUNKS)         // 390,750 bucket-major counters
#define SCANA_BLOCKS ((M_CNT + 1023) / 1024)   // 382

typedef __attribute__((ext_vector_type(8))) short short8;
typedef __attribute__((ext_vector_type(4))) float f32x4;

#define LDS_PITCH 136

__device__ __forceinline__ unsigned short f2bf(float x) {
    unsigned u = __float_as_uint(x);
    return (unsigned short)((u + 0x7FFFu + ((u >> 16) & 1u)) >> 16);  // RNE
}

// ---------------------------------------------------------------------------
// K0: wa1 = W @ a1, wa2 = W @ a2  (keeps f1/f2 exact fp32 in k_gemm)
// ---------------------------------------------------------------------------
__global__ __launch_bounds__(128) void k_wa(
    const float* __restrict__ W, const float* __restrict__ a1,
    const float* __restrict__ a2, float* __restrict__ wa1, float* __restrict__ wa2)
{
    const int k = threadIdx.x;
    float s1 = 0.f, s2 = 0.f;
    #pragma unroll 8
    for (int f = 0; f < OUT_F; f++) {
        const float w = W[k * OUT_F + f];
        s1 += w * a1[f];
        s2 += w * a2[f];
    }
    wa1[k] = s1;
    wa2[k] = s2;
}

// ---------------------------------------------------------------------------
// K1: Wh = h @ W via bf16 MFMA; f1/f2 fused in fp32.  (unchanged, proven)
// ---------------------------------------------------------------------------
__global__ __launch_bounds__(256) void k_gemm(
    const float* __restrict__ h, const float* __restrict__ W,
    const float* __restrict__ wa1, const float* __restrict__ wa2,
    float* __restrict__ Wh, float* __restrict__ f1, float* __restrict__ f2)
{
    __shared__ unsigned short Wt[OUT_F * LDS_PITCH];
    __shared__ unsigned short Al[16 * LDS_PITCH];

    const int tid  = threadIdx.x;
    const int lane = tid & 63;
    const int wav  = tid >> 6;
    const int quad = lane >> 4;
    const int nl   = lane & 15;

    for (int i = tid; i < IN_F * OUT_F; i += 256) {
        const int k = i >> 6, f = i & 63;
        Wt[f * LDS_PITCH + k] = f2bf(W[i]);
    }
    __syncthreads();

    short8 bfrag[4];
    #pragma unroll
    for (int ch = 0; ch < 4; ch++)
        bfrag[ch] = *(const short8*)&Wt[(wav * 16 + nl) * LDS_PITCH + ch * 32 + quad * 8];

    const int srow = tid >> 4;
    const int sc   = tid & 15;
    float w1r[8], w2r[8];
    #pragma unroll
    for (int j = 0; j < 8; j++) { w1r[j] = wa1[sc * 8 + j]; w2r[j] = wa2[sc * 8 + j]; }

    const int ntiles = N_NODES / 16;
    for (int tile = blockIdx.x; tile < ntiles; tile += gridDim.x) {
        const int base = tile * 16;
        __syncthreads();

        const float4 v0 = *(const float4*)&h[(base + srow) * IN_F + sc * 8];
        const float4 v1 = *(const float4*)&h[(base + srow) * IN_F + sc * 8 + 4];
        float p1 = v0.x * w1r[0] + v0.y * w1r[1] + v0.z * w1r[2] + v0.w * w1r[3]
                 + v1.x * w1r[4] + v1.y * w1r[5] + v1.z * w1r[6] + v1.w * w1r[7];
        float p2 = v0.x * w2r[0] + v0.y * w2r[1] + v0.z * w2r[2] + v0.w * w2r[3]
                 + v1.x * w2r[4] + v1.y * w2r[5] + v1.z * w2r[6] + v1.w * w2r[7];
        #pragma unroll
        for (int m = 8; m >= 1; m >>= 1) {
            p1 += __shfl_xor(p1, m, 64);
            p2 += __shfl_xor(p2, m, 64);
        }
        if (sc == 0) { f1[base + srow] = p1; f2[base + srow] = p2; }

        uint4 packed;
        packed.x = (unsigned)f2bf(v0.x) | ((unsigned)f2bf(v0.y) << 16);
        packed.y = (unsigned)f2bf(v0.z) | ((unsigned)f2bf(v0.w) << 16);
        packed.z = (unsigned)f2bf(v1.x) | ((unsigned)f2bf(v1.y) << 16);
        packed.w = (unsigned)f2bf(v1.z) | ((unsigned)f2bf(v1.w) << 16);
        *(uint4*)&Al[srow * LDS_PITCH + sc * 8] = packed;

        __syncthreads();

        f32x4 acc = {0.f, 0.f, 0.f, 0.f};
        #pragma unroll
        for (int ch = 0; ch < 4; ch++) {
            const short8 afrag = *(const short8*)&Al[nl * LDS_PITCH + ch * 32 + quad * 8];
            acc = __builtin_amdgcn_mfma_f32_16x16x32_bf16(afrag, bfrag[ch], acc, 0, 0, 0);
        }

        const int col = wav * 16 + nl;
        #pragma unroll
        for (int r = 0; r < 4; r++)
            Wh[(base + quad * 4 + r) * OUT_F + col] = acc[r];
    }
}

// ---------------------------------------------------------------------------
// K2: per-chunk bucket histogram -> cnt[b * C_CHUNKS + c]  (bucket-major)
// ---------------------------------------------------------------------------
__global__ __launch_bounds__(1024) void k_hist(const int* __restrict__ ei,
                                               int* __restrict__ cnt)
{
    __shared__ int hl[NB];
    const int c = blockIdx.x;
    for (int i = threadIdx.x; i < NB; i += 1024) hl[i] = 0;
    __syncthreads();
    const int e0 = c * CHUNK;
    for (int i = threadIdx.x; i < CHUNK; i += 1024)
        atomicAdd(&hl[ei[e0 + i] >> 6], 1);
    __syncthreads();
    for (int b = threadIdx.x; b < NB; b += 1024)
        cnt[b * C_CHUNKS + c] = hl[b];
}

// ---------------------------------------------------------------------------
// K3a/b/c: exclusive scan of cnt[M_CNT] in place
// ---------------------------------------------------------------------------
__global__ __launch_bounds__(256) void k_scanA(const int* __restrict__ cnt,
                                               int* __restrict__ bsum)
{
    __shared__ int sd[256];
    const int t = threadIdx.x;
    const int i0 = blockIdx.x * 1024 + t * 4;
    int s = 0;
    #pragma unroll
    for (int k = 0; k < 4; k++) {
        const int i = i0 + k;
        s += (i < M_CNT) ? cnt[i] : 0;
    }
    sd[t] = s; __syncthreads();
    for (int off = 128; off >= 1; off >>= 1) {
        if (t < off) sd[t] += sd[t + off];
        __syncthreads();
    }
    if (t == 0) bsum[blockIdx.x] = sd[0];
}

__global__ __launch_bounds__(512) void k_scanB(const int* __restrict__ bsum,
                                               int* __restrict__ bbase)
{
    __shared__ int s[512];
    const int t = threadIdx.x;
    const int mine = (t < SCANA_BLOCKS) ? bsum[t] : 0;
    s[t] = mine; __syncthreads();
    for (int off = 1; off < 512; off <<= 1) {
        const int v = (t >= off) ? s[t - off] : 0;
        __syncthreads();
        s[t] += v;
        __syncthreads();
    }
    if (t < SCANA_BLOCKS) bbase[t] = s[t] - mine;
}

__global__ __launch_bounds__(256) void k_scanC(int* __restrict__ cnt,
                                               const int* __restrict__ bbase)
{
    __shared__ int ts[256];
    const int t = threadIdx.x;
    const int i0 = blockIdx.x * 1024 + t * 4;
    int v[4]; int s = 0;
    #pragma unroll
    for (int k = 0; k < 4; k++) {
        const int i = i0 + k;
        v[k] = (i < M_CNT) ? cnt[i] : 0;
        s += v[k];
    }
    ts[t] = s; __syncthreads();
    for (int off = 1; off < 256; off <<= 1) {
        const int x = (t >= off) ? ts[t - off] : 0;
        __syncthreads();
        ts[t] += x;
        __syncthreads();
    }
    int excl = ts[t] - s + bbase[blockIdx.x];
    #pragma unroll
    for (int k = 0; k < 4; k++) {
        const int i = i0 + k;
        if (i < M_CNT) cnt[i] = excl;
        excl += v[k];
    }
}

// ---------------------------------------------------------------------------
// K4: binned scatter (LDS cursors only, dense bucket-major output)
// pair = {(rlocal<<17)|col, eexp}
// ---------------------------------------------------------------------------
__global__ __launch_bounds__(1024) void k_scatter(
    const int* __restrict__ ei,
    const float* __restrict__ f1,
    const float* __restrict__ f2,
    const int* __restrict__ cnt,
    uint2* __restrict__ pairs)
{
    __shared__ int cur[NB];
    const int c = blockIdx.x;
    for (int b = threadIdx.x; b < NB; b += 1024)
        cur[b] = cnt[b * C_CHUNKS + c];
    __syncthreads();

    const int e0 = c * CHUNK;
    for (int i = threadIdx.x; i < CHUNK; i += 1024) {
        const int r  = ei[e0 + i];
        const int cl = ei[N_EDGES + e0 + i];
        float x = f1[r] + f2[cl];
        x = (x >= 0.f) ? x : 0.2f * x;
        const float ee = __expf(x);
        const int pos = atomicAdd(&cur[r >> 6], 1);
        pairs[pos] = make_uint2(((unsigned)(r & 63) << 17) | (unsigned)cl,
                                __float_as_uint(ee));
    }
}

// ---------------------------------------------------------------------------
// K5: per-bucket streaming row-sort: pairs -> pairs2 (row-grouped) + rowptr.
// Two passes over the bucket's pairs; 64 LDS counters; no capacity limit.
// rowptr[g] = global start of row g's segment; rowptr[N_NODES] = N_EDGES.
// ---------------------------------------------------------------------------
__global__ __launch_bounds__(256) void k_sort(
    const int* __restrict__ cnt,      // scanned; bucket start = cnt[b*C_CHUNKS]
    const uint2* __restrict__ pairs,
    uint2* __restrict__ pairs2,
    int* __restrict__ rowptr)
{
    __shared__ int cnt64[64];
    __shared__ int cur64[64];

    const int b   = blockIdx.x;
    const int tid = threadIdx.x;
    const int start = cnt[b * C_CHUNKS];
    const int end   = (b == NB - 1) ? N_EDGES : cnt[(b + 1) * C_CHUNKS];

    if (tid < 64) cnt64[tid] = 0;
    __syncthreads();

    for (int i = start + tid; i < end; i += 256)
        atomicAdd(&cnt64[pairs[i].x >> 17], 1);
    __syncthreads();

    if (tid < 64) {                       // wave 0: exclusive scan of 64 counts
        const int v = cnt64[tid];
        int s = v;
        #pragma unroll
        for (int off = 1; off < 64; off <<= 1) {
            const int x = __shfl_up(s, off, 64);
            if (tid >= off) s += x;
        }
        cur64[tid] = s - v;               // exclusive
        const int g = b * 64 + tid;
        if (g < N_NODES) rowptr[g] = start + s - v;
    }
    __syncthreads();

    for (int i = start + tid; i < end; i += 256) {
        const uint2 p = pairs[i];
        const int pos = atomicAdd(&cur64[p.x >> 17], 1);
        pairs2[start + pos] = p;
    }
    if (b == 0 && tid == 0) rowptr[N_NODES] = N_EDGES;
}

// ---------------------------------------------------------------------------
// K6: wave-per-node aggregation (round-5 proven structure).
// 4 independent gathers in flight; register accumulation; one row write.
// ---------------------------------------------------------------------------
__global__ __launch_bounds__(256) void k_agg(
    const int* __restrict__ rowptr,
    const uint2* __restrict__ pairs2,
    const float* __restrict__ Wh,
    float* __restrict__ out)
{
    const int wid  = (blockIdx.x * 256 + threadIdx.x) >> 6;
    const int lane = threadIdx.x & 63;
    if (wid >= N_NODES) return;

    const int start = rowptr[wid];
    const int end   = rowptr[wid + 1];

    float acc = 0.f, s = 0.f;
    int j = start;
    for (; j + 4 <= end; j += 4) {
        const uint2 p0 = pairs2[j + 0];
        const uint2 p1 = pairs2[j + 1];
        const uint2 p2 = pairs2[j + 2];
        const uint2 p3 = pairs2[j + 3];
        const float w0 = Wh[((int)(p0.x & 0x1FFFFu) << 6) + lane];
        const float w1 = Wh[((int)(p1.x & 0x1FFFFu) << 6) + lane];
        const float w2 = Wh[((int)(p2.x & 0x1FFFFu) << 6) + lane];
        const float w3 = Wh[((int)(p3.x & 0x1FFFFu) << 6) + lane];
        const float e0 = __uint_as_float(p0.y);
        const float e1 = __uint_as_float(p1.y);
        const float e2 = __uint_as_float(p2.y);
        const float e3 = __uint_as_float(p3.y);
        acc += e0 * w0 + e1 * w1 + e2 * w2 + e3 * w3;
        s   += e0 + e1 + e2 + e3;
    }
    for (; j < end; j++) {
        const uint2 p = pairs2[j];
        const float ee = __uint_as_float(p.y);
        acc += ee * Wh[((int)(p.x & 0x1FFFFu) << 6) + lane];
        s   += ee;
    }

    const float r = acc / (s + 1e-10f);
    out[wid * OUT_F + lane] = (r > 0.f) ? r : expm1f(r);
}

extern "C" void kernel_launch(void* const* d_in, const int* in_sizes, int n_in,
                              void* d_out, int out_size, void* d_ws, size_t ws_size,
                              hipStream_t stream) {
    const float* h  = (const float*)d_in[0];
    const float* W  = (const float*)d_in[1];
    const float* a1 = (const float*)d_in[2];
    const float* a2 = (const float*)d_in[3];
    const int* ei   = (const int*)d_in[4];
    float* out      = (float*)d_out;

    float* ws     = (float*)d_ws;
    float* Wh     = ws;                              // 6,400,000 f
    float* f1     = Wh + N_NODES * OUT_F;            // 100,000
    float* f2     = f1 + N_NODES;                    // 100,000
    float* wa1    = f2 + N_NODES;                    // 128
    float* wa2    = wa1 + 128;                       // 128
    int*   cnt    = (int*)(wa2 + 128);               // 390,750
    int*   bsum   = cnt + M_CNT;                     // 384
    int*   bbase  = bsum + 384;                      // 384
    int*   rowptr = bbase + 384;                     // 100,001
    int*   pad    = rowptr + 100002;
    if ((size_t)(pad - (int*)ws) & 1) pad++;         // 8B align
    uint2* pairs  = (uint2*)pad;                     // 1.6M x 8B
    uint2* pairs2 = pairs + N_EDGES;                 // 1.6M x 8B

    k_wa     <<<1, 128, 0, stream>>>(W, a1, a2, wa1, wa2);
    k_gemm   <<<1250, 256, 0, stream>>>(h, W, wa1, wa2, Wh, f1, f2);
    k_hist   <<<C_CHUNKS, 1024, 0, stream>>>(ei, cnt);
    k_scanA  <<<SCANA_BLOCKS, 256, 0, stream>>>(cnt, bsum);
    k_scanB  <<<1, 512, 0, stream>>>(bsum, bbase);
    k_scanC  <<<SCANA_BLOCKS, 256, 0, stream>>>(cnt, bbase);
    k_scatter<<<C_CHUNKS, 1024, 0, stream>>>(ei, f1, f2, cnt, pairs);
    k_sort   <<<NB, 256, 0, stream>>>(cnt, pairs, pairs2, rowptr);
    k_agg    <<<(N_NODES * 64 + 255) / 256, 256, 0, stream>>>(rowptr, pairs2, Wh, out);
}